// Round 9
// baseline (194.742 us; speedup 1.0000x reference)
//
#include <hip/hip_runtime.h>
#include <hip/hip_fp16.h>
#include <math.h>

#define HH 56
#define WW 56
#define CC 64
#define BB 4
#define HWA (HH*WW)   // 3136

typedef _Float16 half8_t __attribute__((ext_vector_type(8)));
typedef _Float16 h2_t   __attribute__((ext_vector_type(2)));
typedef float f32x4_t __attribute__((ext_vector_type(4)));

// pair layout (padded): xp[b][y 0..56][j 0..56][c] = {v(y,j-1), v(y,j)} fp16.
// Row 56 is never written (poison = finite fp16); reads of it always carry 0 weight.
#define PROWS 57
#define PSTRB (PROWS*57*64*4)    // bytes per batch
#define ROWSTRB (57*64*4)        // bytes per row

// ---------- 1. fused prep: pair rows + conv fp16 layout + weight pack ----------
__global__ __launch_bounds__(256)
void k_prep(const float* __restrict__ x,
            const float* __restrict__ w3, const float* __restrict__ w2,
            const float* __restrict__ b3, const float* __restrict__ b2,
            __half2* __restrict__ xp, _Float16* __restrict__ xh,
            _Float16* __restrict__ Wp, float* __restrict__ bbp) {
    int blk = blockIdx.x;
    int tid = threadIdx.x;
    if (blk < BB*56) {
        __shared__ float ld[64*57];        // [c][xcol] pad 57
        int b = blk / 56, y = blk % 56;
        for (int i = tid; i < 64*56; i += 256) {
            int c = i / 56, col = i % 56;
            ld[c*57 + col] = x[((size_t)b*CC + c)*HWA + y*WW + col];
        }
        __syncthreads();
        for (int i = tid; i < 57*64; i += 256) {
            int j = i >> 6, c = i & 63;
            float lo = (j > 0)  ? ld[c*57 + j - 1] : 0.f;
            float hi = (j < 56) ? ld[c*57 + j]     : 0.f;
            xp[((size_t)(b*PROWS + y)*57 + j)*CC + c] = __floats2half2_rn(lo, hi);
        }
        _Float16* dst = xh + (((size_t)(b*2)*56 + y)*58)*32;
#pragma unroll
        for (int g = 0; g < 2; ++g) {
            for (int i = tid; i < 1856; i += 256) {   // 58*32
                int col = i >> 5, ic = i & 31;
                float v = (col >= 1 && col <= 56) ? ld[(g*32 + ic)*57 + col - 1] : 0.f;
                dst[(size_t)g*(56*58*32) + i] = (_Float16)v;
            }
        }
    } else {
        int i = (blk - BB*56)*256 + tid;
        if (i < 46080) {
            int j    = i & 7;
            int lane = (i >> 3) & 63;
            int mt   = (i >> 9) % 5;
            int kt   = (i / 2560) % 9;
            int g    = i / 23040;
            int m  = mt*16 + (lane & 15);
            int ic = (lane >> 4)*8 + j;
            int ky = kt/3, kx = kt%3;
            float v = 0.f;
            if (m < 49)      v = w3[((g*49 + m)*32 + ic)*9 + ky*3 + kx];
            else if (m < 74) v = w2[((g*25 + (m-49))*32 + ic)*9 + ky*3 + kx];
            Wp[i] = (_Float16)v;
        } else if (i < 46240) {
            int t = i - 46080; int g = t/80, m = t%80;
            float v = 0.f;
            if (m < 49)      v = b3[g*49 + m];
            else if (m < 74) v = b2[g*25 + (m-49)];
            bbp[t] = v;
        }
    }
}

// ---------- 2. MFMA conv: 4 waves/block, one 16-pixel tile per wave ----------
__global__ __launch_bounds__(256)
void k_convmfma(const _Float16* __restrict__ xh, const _Float16* __restrict__ Wp,
                const float* __restrict__ bb,
                float* __restrict__ off3, float* __restrict__ off2) {
    __shared__ _Float16 tile[4][3*18*32];   // 13824 B
    int blk = blockIdx.x;                   // 448
    int iy = blk % 56;
    int g  = (blk / 56) & 1;
    int b  = blk / 112;
    int wv   = threadIdx.y;
    int lane = threadIdx.x;
    int n0 = wv * 16;

    const uint4* xs4 = (const uint4*)xh;
    uint4* tl4 = (uint4*)&tile[wv][0];      // 216 uint4
#pragma unroll
    for (int i = 0; i < 4; ++i) {
        int idx4 = i*64 + lane;
        if (idx4 < 216) {
            int ic4 = idx4 & 3;
            int seg = idx4 >> 2;
            int cl = seg % 18, r = seg / 18;
            int y = iy - 1 + r, col = n0 + cl;
            uint4 v = {0u, 0u, 0u, 0u};
            if (y >= 0 && y < 56 && col < 58)
                v = xs4[((((size_t)(b*2+g)*56 + y)*58 + col) << 2) + ic4];
            tl4[idx4] = v;
        }
    }
    __syncthreads();

    int nlo = lane & 15, khi = lane >> 4;
    f32x4_t acc[5];
#pragma unroll
    for (int mt = 0; mt < 5; ++mt) acc[mt] = (f32x4_t){0.f,0.f,0.f,0.f};

    const half8_t* wp8 = (const half8_t*)Wp;
#pragma unroll
    for (int kt = 0; kt < 9; ++kt) {
        int ky = kt/3, kx = kt%3;
        half8_t bfrag = *(const half8_t*)&tile[wv][((ky*18) + nlo + kx)*32 + khi*8];
#pragma unroll
        for (int mt = 0; mt < 5; ++mt) {
            half8_t afrag = wp8[(((size_t)g*9 + kt)*5 + mt)*64 + lane];
            acc[mt] = __builtin_amdgcn_mfma_f32_16x16x32_f16(afrag, bfrag, acc[mt], 0, 0, 0);
        }
    }

    int pixcol = n0 + nlo;
    if (pixcol < 56) {
        int pix = iy*WW + pixcol;
#pragma unroll
        for (int mt = 0; mt < 5; ++mt) {
#pragma unroll
            for (int r = 0; r < 4; ++r) {
                int m = mt*16 + khi*4 + r;
                if (m < 74) {
                    float val = acc[mt][r] + bb[g*80 + m];
                    if (m < 49)
                        off3[((size_t)b*98 + g*49 + m)*HWA + pix] = val;
                    else
                        off2[((size_t)b*50 + g*25 + (m-49))*HWA + pix] = val;
                }
            }
        }
    }
}

// ---------- 3. deform: 16 px/block (half staging), 4 px/wave, R2 gather core ----------
// Wave yp owns pixels {yp, yp+4, yp+8, yp+12}. Lane t (<K) holds tap-t meta for the 4
// pixels; readlane broadcast; per-lane 4B gathers; unroll 4 => 32 loads in flight (R2
// parity). Block count halves vs R2 (784) => total lw staging traffic + barriers halve.
// partial rows stay 8-px granular so gapA/combine are untouched R2 code.
template<int K, int KS, int PAD, bool WP>
__global__ __launch_bounds__(256)
void k_deform(const _Float16* __restrict__ xp, const float* __restrict__ off,
              const float* __restrict__ wg, const float* __restrict__ bias,
              float* __restrict__ out, float* __restrict__ partial,
              _Float16* __restrict__ xpo) {
    __shared__ float lw[K*65];          // [t][c] padded (R2-proven)
    __shared__ float loffs[2*K][17];    // [row][px 0..15], pad 16->17 (2-way max = free)
    __shared__ float red[16][64];
    int tid = threadIdx.x + threadIdx.y*64;   // 256
    int blk = blockIdx.x;               // BB*HWA/16 = 784
    int xcd = blk & 7;                  // slab: (batch, image-half)
    int idx = blk >> 3;                 // 0..97
    int b   = xcd >> 1;
    int hw0 = (xcd & 1)*(HWA/2) + idx*16;

    for (int i = tid; i < K*64; i += 256) {
        int c = i / K, t = i % K;
        lw[t*65 + c] = wg[i];
    }
    for (int i = tid; i < 8*K; i += 256) {   // 2K rows x 4 float4
        int row = i >> 2, q = i & 3;
        float4 v = *(const float4*)&off[((size_t)b*2*K + row)*HWA + hw0 + q*4];
        loffs[row][q*4 + 0] = v.x; loffs[row][q*4 + 1] = v.y;
        loffs[row][q*4 + 2] = v.z; loffs[row][q*4 + 3] = v.w;
    }
    __syncthreads();

    int yp = threadIdx.y;               // wave handles pixels yp+4s, s=0..3
    int c  = threadIdx.x;

    // per-wave meta in registers: lane t holds tap t's meta for 4 pixels
    int mx[4] = {0,0,0,0}, wz[4] = {0,0,0,0}, ww[4] = {0,0,0,0};
    if (c < K) {
        int t = c;
        int ky = t / KS, kx = t % KS;
#pragma unroll
        for (int s = 0; s < 4; ++s) {
            int p = yp + 4*s;
            int hw = hw0 + p;
            int h = hw / WW, w = hw % WW;
            float py = (float)(h - PAD + 3*ky) + loffs[2*t][p];
            float px = (float)(w - PAD + 3*kx) + loffs[2*t+1][p];
            float y0f = floorf(py), x0f = floorf(px);
            float ly = py - y0f, lx = px - x0f;
            float hy = 1.f - ly, hx = 1.f - lx;
            int y0 = (int)y0f, x0 = (int)x0f;
            int j = x0 + 1;
            bool jv = (j >= 0) && (j <= 56);
            int jc = jv ? j : 0;
            float s0 = ((y0   >= 0) && (y0   < HH) && jv) ? hy : 0.f;
            float s1 = ((y0+1 >= 0) && (y0+1 < HH) && jv) ? ly : 0.f;
            bool use1 = (s0 == 0.f);
            int rbase = use1 ? min(max(y0 + 1, 0), 55) : y0;   // always in [0,55]
            float aw = use1 ? s1 : s0;
            float bw = use1 ? 0.f : s1;
            int mxv = (rbase*57 + jc)*(64*4);   // byte offset of pair elem at c=0
            __half2 wah = __floats2half2_rn(aw*hx, aw*lx);
            __half2 wbh = __floats2half2_rn(bw*hx, bw*lx);
            mx[s] = mxv; wz[s] = *(int*)&wah; ww[s] = *(int*)&wbh;
        }
    }

    const char* xb = (const char*)xp + (size_t)b*PSTRB;   // wave-uniform base
    float acc[4] = {0.f, 0.f, 0.f, 0.f};
#pragma unroll 4
    for (int t = 0; t < K; ++t) {
        float lwv = lw[t*65 + c];
#pragma unroll
        for (int s = 0; s < 4; ++s) {
            int m = (int)__builtin_amdgcn_readlane(mx[s], t);
            int z = (int)__builtin_amdgcn_readlane(wz[s], t);
            int w = (int)__builtin_amdgcn_readlane(ww[s], t);
            const h2_t* r0p = (const h2_t*)(xb + m);
            const h2_t* r1p = (const h2_t*)(xb + m + ROWSTRB);
            h2_t r0 = r0p[c];
            h2_t r1 = r1p[c];
            float v = __builtin_amdgcn_fdot2(r0, *(h2_t*)&z, 0.f, false);
            v = __builtin_amdgcn_fdot2(r1, *(h2_t*)&w, v, false);
            acc[s] = fmaf(v, lwv, acc[s]);
        }
    }

    float bs = bias[c];
#pragma unroll
    for (int s = 0; s < 4; ++s) {
        float val = acc[s] + bs;
        int p  = yp + 4*s;
        int hw = hw0 + p;
        out[((size_t)b*HWA + hw)*CC + c] = val;
        red[p][c] = val;
        if (WP) {                       // pair halves for the next deform's source
            int y = hw / WW, w = hw % WW;
            _Float16* base = xpo + ((size_t)(b*PROWS + y)*57)*CC*2;
            _Float16 hv = (_Float16)val;
            base[((w    )*64 + c)*2 + 1] = hv;      // slot w hi
            base[((w + 1)*64 + c)*2 + 0] = hv;      // slot w+1 lo
            if (w == 0)  base[(c)*2 + 0] = (_Float16)0.f;
            if (w == 55) base[((56)*64 + c)*2 + 1] = (_Float16)0.f;
        }
    }

    __syncthreads();
    if (yp == 0) {
        float s = red[0][c] + red[1][c] + red[2][c] + red[3][c]
                + red[4][c] + red[5][c] + red[6][c] + red[7][c];
        partial[((size_t)b*(HWA/8) + (hw0 >> 3))*64 + c] = s;
    } else if (yp == 1) {
        float s = red[8][c] + red[9][c] + red[10][c] + red[11][c]
                + red[12][c] + red[13][c] + red[14][c] + red[15][c];
        partial[((size_t)b*(HWA/8) + (hw0 >> 3) + 1)*64 + c] = s;
    }
}

// ---------- 4. GAP stage A: 112 blocks, 28 partial rows each (R2 exact) ----------
__global__ void k_gapA(const float* __restrict__ p1, const float* __restrict__ p2,
                       float* __restrict__ g2) {
    __shared__ float red[4][64];
    int blk = blockIdx.x;              // 8bf * 14chunk
    int chunk = blk % 14;
    int bf    = blk / 14;
    int b     = bf >> 1;
    const float* p = (bf & 1) ? p2 : p1;
    int tid = threadIdx.x;             // 256
    int c = tid & 63, s = tid >> 6;
    float sum = 0.f;
#pragma unroll
    for (int i = 0; i < 7; ++i) {
        int j = chunk*28 + s + 4*i;
        sum += p[((size_t)b*(HWA/8) + j)*64 + c];
    }
    red[s][c] = sum;
    __syncthreads();
    if (s == 0)
        g2[((size_t)bf*14 + chunk)*64 + c]
            = red[0][c] + red[1][c] + red[2][c] + red[3][c];
}

// ---------- 5. softmax gate + combine (R2 exact: 64-px blocks, float4 loads) ----------
__global__ void k_combine(const float* __restrict__ o1, const float* __restrict__ o2,
                          const float* __restrict__ g2, float* __restrict__ out) {
    __shared__ float tile[64][65];
    __shared__ float ash[2][64];
    int blk = blockIdx.x;              // BB * (HWA/64)
    int b   = blk / (HWA/64);
    int t0  = (blk % (HWA/64)) * 64;
    int tid = threadIdx.x;             // 256

    if (tid < 64) {
        int cc = tid;
        float s1 = 0.f, s2 = 0.f;
#pragma unroll
        for (int k = 0; k < 14; ++k) {
            s1 += g2[((size_t)(b*2+0)*14 + k)*64 + cc];
            s2 += g2[((size_t)(b*2+1)*14 + k)*64 + cc];
        }
        s1 *= (1.f/HWA); s2 *= (1.f/HWA);
        float m  = fmaxf(s1, s2);
        float e1 = expf(s1 - m), e2 = expf(s2 - m);
        float a1 = e1 / (e1 + e2);
        ash[0][cc] = a1;
        ash[1][cc] = 1.f - a1;
    }
    __syncthreads();

    const float4* o14 = (const float4*)o1;
    const float4* o24 = (const float4*)o2;
#pragma unroll
    for (int i = 0; i < 4; ++i) {
        int f = i*256 + tid;           // 1024 float4 chunks = 64px * 16
        int p = f >> 4, c4 = f & 15;
        size_t idx4 = (((size_t)b*HWA + t0 + p)*CC >> 2) + c4;
        float4 v1 = o14[idx4];
        float4 v2 = o24[idx4];
        float4 a1 = *(const float4*)&ash[0][c4*4];
        float4 a2 = *(const float4*)&ash[1][c4*4];
        tile[p][c4*4 + 0] = v1.x*a1.x + v2.x*a2.x;
        tile[p][c4*4 + 1] = v1.y*a1.y + v2.y*a2.y;
        tile[p][c4*4 + 2] = v1.z*a1.z + v2.z*a2.z;
        tile[p][c4*4 + 3] = v1.w*a1.w + v2.w*a2.w;
    }
    __syncthreads();
    int q = tid >> 6, p2 = tid & 63;
#pragma unroll
    for (int i = 0; i < 16; ++i) {
        int c2 = q + 4*i;
        out[((size_t)b*CC + c2)*HWA + t0 + p2] = tile[p2][c2];
    }
}

extern "C" void kernel_launch(void* const* d_in, const int* in_sizes, int n_in,
                              void* d_out, int out_size, void* d_ws, size_t ws_size,
                              hipStream_t stream) {
    const float* x      = (const float*)d_in[0];
    const float* w_off3 = (const float*)d_in[1];
    const float* b_off3 = (const float*)d_in[2];
    const float* w_off2 = (const float*)d_in[3];
    const float* b_off2 = (const float*)d_in[4];
    const float* w7     = (const float*)d_in[5];
    const float* b7     = (const float*)d_in[6];
    const float* w5     = (const float*)d_in[7];
    const float* b5     = (const float*)d_in[8];
    float* out = (float*)d_out;

    const size_t PAIRF = (size_t)BB*PROWS*57*64;
    float* ws    = (float*)d_ws;
    float* off3r = ws;                    // 1229312
    float* off2r = off3r + 1229312;       // 627200
    float* out1  = off2r + 627200;        // 802816
    float* out2  = out1  + 802816;        // 802816
    float* xp1f  = out2  + 802816;        // 831744
    float* xp2f  = xp1f  + PAIRF;         // 831744
    float* xhf   = xp2f  + PAIRF;         // 415744 (831488 fp16)
    float* part1 = xhf   + 415744;        // 100352 (b*392*64)
    float* part2 = part1 + 100352;        // 100352
    float* gpA   = part2 + 100352;        // 7168
    float* wpf   = gpA   + 7168;          // 23040 (46080 fp16)
    float* bbp   = wpf   + 23040;         // 160
    __half2*  xp1  = (__half2*)xp1f;
    _Float16* xp2h = (_Float16*)xp2f;
    _Float16* xh   = (_Float16*)xhf;
    _Float16* Wp   = (_Float16*)wpf;
    size_t need = (size_t)(1229312 + 627200 + 802816*2 + 831744*2 + 415744
                           + 100352*2 + 7168 + 23040 + 160) * 4;
    if (ws_size < need) return;

    // 1: fused prep (pair layout + conv fp16 layout + weight pack)
    k_prep<<<BB*56 + 181, 256, 0, stream>>>(x, w_off3, w_off2, b_off3, b_off2,
                                            xp1, xh, Wp, bbp);
    // 2: both grouped convs via MFMA
    k_convmfma<<<BB*2*56, dim3(64,4), 0, stream>>>(xh, Wp, bbp, off3r, off2r);
    // 3: deform1 (16 px/block; writes out1 + xp2 pairs + gap partials)
    k_deform<49,7,9,true><<<BB*(HWA/16), dim3(64,4), 0, stream>>>(
        (const _Float16*)xp1, off3r, w7, b7, out1, part1, xp2h);
    // 4: deform2
    k_deform<25,5,6,false><<<BB*(HWA/16), dim3(64,4), 0, stream>>>(
        xp2h, off2r, w5, b5, out2, part2, nullptr);
    // 5: GAP stage A
    k_gapA<<<8*14, 256, 0, stream>>>(part1, part2, gpA);
    // 6: combine (finishes GAP, softmax gate, NHWC->NCHW)
    k_combine<<<BB*(HWA/64), 256, 0, stream>>>(out1, out2, gpA, out);
}

// Round 10
// 133.933 us; speedup vs baseline: 1.4540x; 1.4540x over previous
//
#include <hip/hip_runtime.h>
#include <hip/hip_fp16.h>
#include <math.h>

#define HH 56
#define WW 56
#define CC 64
#define BB 4
#define HWA (HH*WW)   // 3136

typedef _Float16 half8_t __attribute__((ext_vector_type(8)));
typedef _Float16 h2_t   __attribute__((ext_vector_type(2)));
typedef float f32x4_t __attribute__((ext_vector_type(4)));

// pair layout (padded): xp[b][y 0..56][j 0..56][c] = {v(y,j-1), v(y,j)} fp16.
// Row 56 is never written (poison = finite fp16); reads of it always carry 0 weight.
#define PROWS 57
#define PSTRB (PROWS*57*64*4)    // bytes per batch
#define ROWSTRB (57*64*4)        // bytes per row

// ---------- 1. fused prep: pair rows + conv fp16 layout + weight pack ----------
__global__ __launch_bounds__(256)
void k_prep(const float* __restrict__ x,
            const float* __restrict__ w3, const float* __restrict__ w2,
            const float* __restrict__ b3, const float* __restrict__ b2,
            __half2* __restrict__ xp, _Float16* __restrict__ xh,
            _Float16* __restrict__ Wp, float* __restrict__ bbp) {
    int blk = blockIdx.x;
    int tid = threadIdx.x;
    if (blk < BB*56) {
        __shared__ float ld[64*57];        // [c][xcol] pad 57
        int b = blk / 56, y = blk % 56;
        for (int i = tid; i < 64*56; i += 256) {
            int c = i / 56, col = i % 56;
            ld[c*57 + col] = x[((size_t)b*CC + c)*HWA + y*WW + col];
        }
        __syncthreads();
        for (int i = tid; i < 57*64; i += 256) {
            int j = i >> 6, c = i & 63;
            float lo = (j > 0)  ? ld[c*57 + j - 1] : 0.f;
            float hi = (j < 56) ? ld[c*57 + j]     : 0.f;
            xp[((size_t)(b*PROWS + y)*57 + j)*CC + c] = __floats2half2_rn(lo, hi);
        }
        _Float16* dst = xh + (((size_t)(b*2)*56 + y)*58)*32;
#pragma unroll
        for (int g = 0; g < 2; ++g) {
            for (int i = tid; i < 1856; i += 256) {   // 58*32, r = col*32+ic
                int col = i >> 5, ic = i & 31;
                float v = (col >= 1 && col <= 56) ? ld[(g*32 + ic)*57 + col - 1] : 0.f;
                dst[(size_t)g*(56*58*32) + i] = (_Float16)v;
            }
        }
    } else {
        int i = (blk - BB*56)*256 + tid;
        if (i < 46080) {
            int j    = i & 7;
            int lane = (i >> 3) & 63;
            int mt   = (i >> 9) % 5;
            int kt   = (i / 2560) % 9;
            int g    = i / 23040;
            int m  = mt*16 + (lane & 15);
            int ic = (lane >> 4)*8 + j;
            int ky = kt/3, kx = kt%3;
            float v = 0.f;
            if (m < 49)      v = w3[((g*49 + m)*32 + ic)*9 + ky*3 + kx];
            else if (m < 74) v = w2[((g*25 + (m-49))*32 + ic)*9 + ky*3 + kx];
            Wp[i] = (_Float16)v;
        } else if (i < 46240) {
            int t = i - 46080; int g = t/80, m = t%80;
            float v = 0.f;
            if (m < 49)      v = b3[g*49 + m];
            else if (m < 74) v = b2[g*25 + (m-49)];
            bbp[t] = v;
        }
    }
}

// ---------- 2. MFMA conv: 4 waves/block, one 16-pixel tile per wave ----------
// staging vectorized: 216 uint4 loads (one bounds check per 16B granule) vs 864 scalar
__global__ __launch_bounds__(256)
void k_convmfma(const _Float16* __restrict__ xh, const _Float16* __restrict__ Wp,
                const float* __restrict__ bb,
                float* __restrict__ off3, float* __restrict__ off2) {
    __shared__ _Float16 tile[4][3*18*32];   // 13824 B
    int blk = blockIdx.x;                   // 448
    int iy = blk % 56;
    int g  = (blk / 56) & 1;
    int b  = blk / 112;
    int wv   = threadIdx.y;                 // 0..3 = nq
    int lane = threadIdx.x;
    int n0 = wv * 16;

    const uint4* xs4 = (const uint4*)xh;
    uint4* tl4 = (uint4*)&tile[wv][0];      // 216 uint4
#pragma unroll
    for (int i = 0; i < 4; ++i) {
        int idx4 = i*64 + lane;
        if (idx4 < 216) {
            int ic4 = idx4 & 3;
            int seg = idx4 >> 2;            // 0..53
            int cl = seg % 18, r = seg / 18;
            int y = iy - 1 + r, col = n0 + cl;
            uint4 v = {0u, 0u, 0u, 0u};
            if (y >= 0 && y < 56 && col < 58)
                v = xs4[((((size_t)(b*2+g)*56 + y)*58 + col) << 2) + ic4];
            tl4[idx4] = v;
        }
    }
    __syncthreads();

    int nlo = lane & 15, khi = lane >> 4;
    f32x4_t acc[5];
#pragma unroll
    for (int mt = 0; mt < 5; ++mt) acc[mt] = (f32x4_t){0.f,0.f,0.f,0.f};

    const half8_t* wp8 = (const half8_t*)Wp;
#pragma unroll
    for (int kt = 0; kt < 9; ++kt) {
        int ky = kt/3, kx = kt%3;
        half8_t bfrag = *(const half8_t*)&tile[wv][((ky*18) + nlo + kx)*32 + khi*8];
#pragma unroll
        for (int mt = 0; mt < 5; ++mt) {
            half8_t afrag = wp8[(((size_t)g*9 + kt)*5 + mt)*64 + lane];
            acc[mt] = __builtin_amdgcn_mfma_f32_16x16x32_f16(afrag, bfrag, acc[mt], 0, 0, 0);
        }
    }

    int pixcol = n0 + nlo;
    if (pixcol < 56) {
        int pix = iy*WW + pixcol;
#pragma unroll
        for (int mt = 0; mt < 5; ++mt) {
#pragma unroll
            for (int r = 0; r < 4; ++r) {
                int m = mt*16 + khi*4 + r;
                if (m < 74) {
                    float val = acc[mt][r] + bb[g*80 + m];
                    if (m < 49)
                        off3[((size_t)b*98 + g*49 + m)*HWA + pix] = val;
                    else
                        off2[((size_t)b*50 + g*25 + (m-49))*HWA + pix] = val;
                }
            }
        }
    }
}

// ---------- 3. deform: 8 px/block, 2 px/wave; lane-distributed meta, readlane broadcast ----------
// R2-proven optimum: hot loop has ZERO lmeta LDS traffic; lane t (< K) holds tap t's
// {byte-offset, wa, wb} in registers; readlane (dynamic-uniform) broadcasts to SGPRs;
// gather addresses are SGPR-base + loop-invariant per-lane c*4 voffset; unroll 8.
template<int K, int KS, int PAD, bool WP>
__global__ __launch_bounds__(256)
void k_deform(const _Float16* __restrict__ xp, const float* __restrict__ off,
              const float* __restrict__ wg, const float* __restrict__ bias,
              float* __restrict__ out, float* __restrict__ partial,
              _Float16* __restrict__ xpo) {
    __shared__ float lw[K*65];          // [t][c] padded
    __shared__ float loffs[2*K][9];     // pad 8->9
    __shared__ float red[8][64];
    int tid = threadIdx.x + threadIdx.y*64;   // 256
    int blk = blockIdx.x;               // BB*HWA/8 = 1568
    int xcd = blk & 7;                  // slab: (batch, image-half)
    int idx = blk >> 3;
    int b   = xcd >> 1;
    int hw0 = (xcd & 1)*(HWA/2) + idx*8;

    for (int i = tid; i < K*64; i += 256) {
        int c = i / K, t = i % K;
        lw[t*65 + c] = wg[i];
    }
    for (int i = tid; i < 4*K; i += 256) {   // 2K rows x 2 float4
        int row = i >> 1, half = i & 1;
        float4 v = *(const float4*)&off[((size_t)b*2*K + row)*HWA + hw0 + half*4];
        loffs[row][half*4 + 0] = v.x; loffs[row][half*4 + 1] = v.y;
        loffs[row][half*4 + 2] = v.z; loffs[row][half*4 + 3] = v.w;
    }
    __syncthreads();

    int yp = threadIdx.y;               // wave handles pixels yp and yp+4
    int c  = threadIdx.x;

    // per-wave meta in registers: lane t computes tap t for pixels yp, yp+4
    int mx0 = 0, wz0 = 0, ww0 = 0;      // pixel yp
    int mx1 = 0, wz1 = 0, ww1 = 0;      // pixel yp+4
    if (c < K) {
        int t = c;
        int ky = t / KS, kx = t % KS;
#pragma unroll
        for (int s = 0; s < 2; ++s) {
            int p = yp + 4*s;
            int hw = hw0 + p;
            int h = hw / WW, w = hw % WW;
            float py = (float)(h - PAD + 3*ky) + loffs[2*t][p];
            float px = (float)(w - PAD + 3*kx) + loffs[2*t+1][p];
            float y0f = floorf(py), x0f = floorf(px);
            float ly = py - y0f, lx = px - x0f;
            float hy = 1.f - ly, hx = 1.f - lx;
            int y0 = (int)y0f, x0 = (int)x0f;
            int j = x0 + 1;
            bool jv = (j >= 0) && (j <= 56);
            int jc = jv ? j : 0;
            float s0 = ((y0   >= 0) && (y0   < HH) && jv) ? hy : 0.f;
            float s1 = ((y0+1 >= 0) && (y0+1 < HH) && jv) ? ly : 0.f;
            bool use1 = (s0 == 0.f);
            int rbase = use1 ? min(max(y0 + 1, 0), 55) : y0;   // always in [0,55]
            float aw = use1 ? s1 : s0;
            float bw = use1 ? 0.f : s1;
            int mxv = (rbase*57 + jc)*(64*4);   // byte offset of pair elem at c=0
            __half2 wah = __floats2half2_rn(aw*hx, aw*lx);
            __half2 wbh = __floats2half2_rn(bw*hx, bw*lx);
            if (s == 0) { mx0 = mxv; wz0 = *(int*)&wah; ww0 = *(int*)&wbh; }
            else        { mx1 = mxv; wz1 = *(int*)&wah; ww1 = *(int*)&wbh; }
        }
    }

    const char* xb = (const char*)xp + (size_t)b*PSTRB;   // wave-uniform base
    float acc0 = 0.f, acc1 = 0.f;
#pragma unroll 8
    for (int t = 0; t < K; ++t) {
        int m0 = (int)__builtin_amdgcn_readlane(mx0, t);
        int z0 = (int)__builtin_amdgcn_readlane(wz0, t);
        int w0 = (int)__builtin_amdgcn_readlane(ww0, t);
        int m1 = (int)__builtin_amdgcn_readlane(mx1, t);
        int z1 = (int)__builtin_amdgcn_readlane(wz1, t);
        int w1 = (int)__builtin_amdgcn_readlane(ww1, t);
        const h2_t* r0p = (const h2_t*)(xb + m0);
        const h2_t* r1p = (const h2_t*)(xb + m0 + ROWSTRB);
        const h2_t* r2p = (const h2_t*)(xb + m1);
        const h2_t* r3p = (const h2_t*)(xb + m1 + ROWSTRB);
        h2_t r0a = r0p[c];
        h2_t r1a = r1p[c];
        h2_t r0b = r2p[c];
        h2_t r1b = r3p[c];
        float lwv = lw[t*65 + c];
        float v0 = __builtin_amdgcn_fdot2(r0a, *(h2_t*)&z0, 0.f, false);
        v0 = __builtin_amdgcn_fdot2(r1a, *(h2_t*)&w0, v0, false);
        float v1 = __builtin_amdgcn_fdot2(r0b, *(h2_t*)&z1, 0.f, false);
        v1 = __builtin_amdgcn_fdot2(r1b, *(h2_t*)&w1, v1, false);
        acc0 = fmaf(v0, lwv, acc0);
        acc1 = fmaf(v1, lwv, acc1);
    }
    float bs = bias[c];
    float val0 = acc0 + bs;
    float val1 = acc1 + bs;
    int hwA = hw0 + yp, hwB = hw0 + yp + 4;
    out[((size_t)b*HWA + hwA)*CC + c] = val0;
    out[((size_t)b*HWA + hwB)*CC + c] = val1;

    if (WP) {                           // pair halves for the next deform's source
#pragma unroll
        for (int s = 0; s < 2; ++s) {
            int hw = s ? hwB : hwA;
            float val = s ? val1 : val0;
            int y = hw / WW, w = hw % WW;
            _Float16* base = xpo + ((size_t)(b*PROWS + y)*57)*CC*2;
            _Float16 hv = (_Float16)val;
            base[((w    )*64 + c)*2 + 1] = hv;      // slot w hi
            base[((w + 1)*64 + c)*2 + 0] = hv;      // slot w+1 lo
            if (w == 0)  base[(c)*2 + 0] = (_Float16)0.f;
            if (w == 55) base[((56)*64 + c)*2 + 1] = (_Float16)0.f;
        }
    }

    red[yp][c] = val0;
    red[yp + 4][c] = val1;
    __syncthreads();
    if (yp == 0) {
        float s = red[0][c] + red[1][c] + red[2][c] + red[3][c]
                + red[4][c] + red[5][c] + red[6][c] + red[7][c];
        partial[((size_t)b*(HWA/8) + (hw0 >> 3))*64 + c] = s;
    }
}

// ---------- 4. GAP stage A: 112 blocks, 28 partial rows each ----------
__global__ void k_gapA(const float* __restrict__ p1, const float* __restrict__ p2,
                       float* __restrict__ g2) {
    __shared__ float red[4][64];
    int blk = blockIdx.x;              // 8bf * 14chunk
    int chunk = blk % 14;
    int bf    = blk / 14;
    int b     = bf >> 1;
    const float* p = (bf & 1) ? p2 : p1;
    int tid = threadIdx.x;             // 256
    int c = tid & 63, s = tid >> 6;
    float sum = 0.f;
#pragma unroll
    for (int i = 0; i < 7; ++i) {
        int j = chunk*28 + s + 4*i;
        sum += p[((size_t)b*(HWA/8) + j)*64 + c];
    }
    red[s][c] = sum;
    __syncthreads();
    if (s == 0)
        g2[((size_t)bf*14 + chunk)*64 + c]
            = red[0][c] + red[1][c] + red[2][c] + red[3][c];
}

// ---------- 5. softmax gate + combine (float4 loads, gate factors in LDS) ----------
__global__ void k_combine(const float* __restrict__ o1, const float* __restrict__ o2,
                          const float* __restrict__ g2, float* __restrict__ out) {
    __shared__ float tile[64][65];
    __shared__ float ash[2][64];
    int blk = blockIdx.x;              // BB * (HWA/64)
    int b   = blk / (HWA/64);
    int t0  = (blk % (HWA/64)) * 64;
    int tid = threadIdx.x;             // 256

    if (tid < 64) {
        int cc = tid;
        float s1 = 0.f, s2 = 0.f;
#pragma unroll
        for (int k = 0; k < 14; ++k) {
            s1 += g2[((size_t)(b*2+0)*14 + k)*64 + cc];
            s2 += g2[((size_t)(b*2+1)*14 + k)*64 + cc];
        }
        s1 *= (1.f/HWA); s2 *= (1.f/HWA);
        float m  = fmaxf(s1, s2);
        float e1 = expf(s1 - m), e2 = expf(s2 - m);
        float a1 = e1 / (e1 + e2);
        ash[0][cc] = a1;
        ash[1][cc] = 1.f - a1;
    }
    __syncthreads();

    const float4* o14 = (const float4*)o1;
    const float4* o24 = (const float4*)o2;
#pragma unroll
    for (int i = 0; i < 4; ++i) {
        int f = i*256 + tid;           // 1024 float4 chunks = 64px * 16
        int p = f >> 4, c4 = f & 15;
        size_t idx4 = (((size_t)b*HWA + t0 + p)*CC >> 2) + c4;
        float4 v1 = o14[idx4];
        float4 v2 = o24[idx4];
        float4 a1 = *(const float4*)&ash[0][c4*4];
        float4 a2 = *(const float4*)&ash[1][c4*4];
        tile[p][c4*4 + 0] = v1.x*a1.x + v2.x*a2.x;
        tile[p][c4*4 + 1] = v1.y*a1.y + v2.y*a2.y;
        tile[p][c4*4 + 2] = v1.z*a1.z + v2.z*a2.z;
        tile[p][c4*4 + 3] = v1.w*a1.w + v2.w*a2.w;
    }
    __syncthreads();
    int q = tid >> 6, p2 = tid & 63;
#pragma unroll
    for (int i = 0; i < 16; ++i) {
        int c2 = q + 4*i;
        out[((size_t)b*CC + c2)*HWA + t0 + p2] = tile[p2][c2];
    }
}

extern "C" void kernel_launch(void* const* d_in, const int* in_sizes, int n_in,
                              void* d_out, int out_size, void* d_ws, size_t ws_size,
                              hipStream_t stream) {
    const float* x      = (const float*)d_in[0];
    const float* w_off3 = (const float*)d_in[1];
    const float* b_off3 = (const float*)d_in[2];
    const float* w_off2 = (const float*)d_in[3];
    const float* b_off2 = (const float*)d_in[4];
    const float* w7     = (const float*)d_in[5];
    const float* b7     = (const float*)d_in[6];
    const float* w5     = (const float*)d_in[7];
    const float* b5     = (const float*)d_in[8];
    float* out = (float*)d_out;

    const size_t PAIRF = (size_t)BB*PROWS*57*64;
    float* ws    = (float*)d_ws;
    float* off3r = ws;                    // 1229312
    float* off2r = off3r + 1229312;       // 627200
    float* out1  = off2r + 627200;        // 802816
    float* out2  = out1  + 802816;        // 802816
    float* xp1f  = out2  + 802816;        // 831744
    float* xp2f  = xp1f  + PAIRF;         // 831744
    float* xhf   = xp2f  + PAIRF;         // 415744 (831488 fp16)
    float* part1 = xhf   + 415744;        // 100352 (b*392*64)
    float* part2 = part1 + 100352;        // 100352
    float* gpA   = part2 + 100352;        // 7168
    float* wpf   = gpA   + 7168;          // 23040 (46080 fp16)
    float* bbp   = wpf   + 23040;         // 160
    __half2*  xp1 = (__half2*)xp1f;
    _Float16* xp2h = (_Float16*)xp2f;
    _Float16* xh  = (_Float16*)xhf;
    _Float16* Wp  = (_Float16*)wpf;
    size_t need = (size_t)(1229312 + 627200 + 802816*2 + 831744*2 + 415744
                           + 100352*2 + 7168 + 23040 + 160) * 4;
    if (ws_size < need) return;

    // 1: fused prep (pair layout + conv fp16 layout + weight pack)
    k_prep<<<BB*56 + 181, 256, 0, stream>>>(x, w_off3, w_off2, b_off3, b_off2,
                                            xp1, xh, Wp, bbp);
    // 2: both grouped convs via MFMA
    k_convmfma<<<BB*2*56, dim3(64,4), 0, stream>>>(xh, Wp, bbp, off3r, off2r);
    // 3: deform1 (8 px/block; writes out1 + xp2 pairs + gap partials)
    k_deform<49,7,9,true><<<BB*(HWA/8), dim3(64,4), 0, stream>>>(
        (const _Float16*)xp1, off3r, w7, b7, out1, part1, xp2h);
    // 4: deform2
    k_deform<25,5,6,false><<<BB*(HWA/8), dim3(64,4), 0, stream>>>(
        xp2h, off2r, w5, b5, out2, part2, nullptr);
    // 5: GAP stage A
    k_gapA<<<8*14, 256, 0, stream>>>(part1, part2, gpA);
    // 6: combine (finishes GAP, softmax gate, NHWC->NCHW)
    k_combine<<<BB*(HWA/64), 256, 0, stream>>>(out1, out2, gpA, out);
}